// Round 6
// baseline (48.759 us; speedup 1.0000x reference)
//
#include <hip/hip_runtime.h>
#include <hip/hip_bf16.h>
#include <math.h>

#define BATCH_C 16384
#define SPW 4   // segments per wave

typedef float f32x4  __attribute__((ext_vector_type(4)));
typedef f32x4 __attribute__((aligned(4))) f32x4_u;   // dword-aligned vector load
typedef float f32x16 __attribute__((ext_vector_type(16)));
typedef short s16x8  __attribute__((ext_vector_type(8)));

static __device__ inline short f2bf(float x) {
    __hip_bfloat16 h = __float2bfloat16(x);   // RNE
    union { __hip_bfloat16 b; short s; } u; u.b = h; return u.s;
}
static __device__ inline float bf2f(short s) {
    unsigned u = ((unsigned)(unsigned short)s) << 16;
    union { unsigned u32; float f; } c; c.u32 = u; return c.f;
}

// ---------------------------------------------------------------------------
// Kernel 1: segment boundary detection for BOTH sides (grid.y = side).
// start[b] = first index i with seg[i] >= b; start[BATCH]=n.
// ---------------------------------------------------------------------------
__global__ __launch_bounds__(256) void seg_starts_kernel(
    const int* __restrict__ lseg, const int* __restrict__ rseg, int n,
    int* __restrict__ lstart, int* __restrict__ rstart)
{
    const int* __restrict__ seg = blockIdx.y ? rseg : lseg;
    int* __restrict__ start = blockIdx.y ? rstart : lstart;
    int i = blockIdx.x * blockDim.x + threadIdx.x;
    if (i >= n) return;
    int s = seg[i];
    int prev = (i == 0) ? -1 : seg[i - 1];
    for (int b = prev + 1; b <= s; ++b) start[b] = i;
    if (i == n - 1) {
        for (int b = s + 1; b <= BATCH_C; ++b) start[b] = n;
    }
}

// ---------------------------------------------------------------------------
// Kernel 2: fused per-unit MLP (9->64, ReLU) + ragged segment sum via MFMA.
// fp32 exactness via bf16 3-term split: A*B ~= Ah*Bh + Ah*Bl + Al*Bh.
// One 32-unit window = one M-tile of v_mfma_f32_32x32x16_bf16 (x2 N-tiles
// of 32 channels, x3 split terms = 6 MFMA/window). K=16 holds feats k=0..8,
// a ones-column at k=9 with bias as B-row 9 (bias exact via hi+lo), k>=10
// zero. Invalid rows (unit >= segment end) have A==0 -> C row==0 ->
// relu(0)=0 -> full row-sum always valid. Windows tile each segment;
// A-fragments load straight from global (no LDS), prefetched 1 window ahead.
// A layout (32x32x16): row = lane&31, k = (lane>>5)*8 + i (contiguous 8).
// B layout:            col = lane&31, k = (lane>>5)*8 + i.
// C/D layout (HW-verified m74/m101): col = lane&31,
//                                    row = (reg&3) + 8*(reg>>2) + 4*(lane>>5).
// Epilogue per window: relu + sum of 16 C regs per N-tile; per segment:
// shfl_xor(32) to merge row-halves, one store per lane (exactly-once).
// ---------------------------------------------------------------------------
__global__ __launch_bounds__(256, 4) void pool_kernel(
    const float* __restrict__ lfeats, const float* __restrict__ rfeats,
    const int* __restrict__ lstart, const int* __restrict__ rstart,
    const float* __restrict__ W1, const float* __restrict__ b1,
    float* __restrict__ pooled, int nunits)
{
    const int lane = threadIdx.x & 63;
    const int wv   = threadIdx.x >> 6;
    const int side = blockIdx.y;
    const int S0   = (blockIdx.x * 4 + wv) * SPW;
    const int r    = lane & 31;   // A row / B col within tile
    const int h    = lane >> 5;   // k-half: h=0 -> k 0..7, h=1 -> k 8..15

    const float* __restrict__ feats = side ? rfeats : lfeats;
    const int*   __restrict__ start = side ? rstart : lstart;

    // ---- B fragments (weights + bias row), built once per wave ----
    s16x8 bh[2], bl[2];
#pragma unroll
    for (int n = 0; n < 2; ++n) {
        const int col = n * 32 + r;
#pragma unroll
        for (int i = 0; i < 8; ++i) {
            const int k = h * 8 + i;
            float v = 0.0f;
            if (k < 9) v = W1[k * 64 + col];
            else if (k == 9) v = b1[col];
            short vh = f2bf(v);
            bh[n][i] = vh;
            bl[n][i] = f2bf(v - bf2f(vh));
        }
    }

    int sv = start[S0 + (lane <= SPW ? lane : SPW)];
    const int s_abs   = __shfl(sv, 0, 64);
    const int end_abs = __shfl(sv, SPW, 64);

    // prefetch registers: h==0 lanes hold feats[u][0..7]; h==1 hold [8] in pf[0]
    float pf0, pf1, pf2, pf3, pf4, pf5, pf6, pf7;
    pf0 = pf1 = pf2 = pf3 = pf4 = pf5 = pf6 = pf7 = 0.0f;

    auto PF = [&](int wb) {
        int u = wb + r;
        if (u > nunits - 1) u = nunits - 1;
        const float* __restrict__ p = feats + (size_t)u * 9;
        if (h == 0) {
            f32x4 x0 = *reinterpret_cast<const f32x4_u*>(p);
            f32x4 x1 = *reinterpret_cast<const f32x4_u*>(p + 4);
            pf0 = x0.x; pf1 = x0.y; pf2 = x0.z; pf3 = x0.w;
            pf4 = x1.x; pf5 = x1.y; pf6 = x1.z; pf7 = x1.w;
        } else {
            pf0 = p[8];
        }
    };

    if (s_abs < end_abs) PF(s_abs);

    for (int c = 0; c < SPW; ++c) {
        const int sc = __shfl(sv, c, 64);
        const int ec = __shfl(sv, c + 1, 64);
        float acc0 = 0.0f, acc1 = 0.0f;

        int base = sc;
        while (base < ec) {
            const int cnt = (ec - base < 32) ? (ec - base) : 32;
            const bool valid = r < cnt;

            // ---- build A fragments from prefetched floats ----
            s16x8 ah = (s16x8)0, al = (s16x8)0;
            if (h == 0) {
                float v0 = valid ? pf0 : 0.f, v1 = valid ? pf1 : 0.f;
                float v2 = valid ? pf2 : 0.f, v3 = valid ? pf3 : 0.f;
                float v4 = valid ? pf4 : 0.f, v5 = valid ? pf5 : 0.f;
                float v6 = valid ? pf6 : 0.f, v7 = valid ? pf7 : 0.f;
                short t;
                t = f2bf(v0); ah[0] = t; al[0] = f2bf(v0 - bf2f(t));
                t = f2bf(v1); ah[1] = t; al[1] = f2bf(v1 - bf2f(t));
                t = f2bf(v2); ah[2] = t; al[2] = f2bf(v2 - bf2f(t));
                t = f2bf(v3); ah[3] = t; al[3] = f2bf(v3 - bf2f(t));
                t = f2bf(v4); ah[4] = t; al[4] = f2bf(v4 - bf2f(t));
                t = f2bf(v5); ah[5] = t; al[5] = f2bf(v5 - bf2f(t));
                t = f2bf(v6); ah[6] = t; al[6] = f2bf(v6 - bf2f(t));
                t = f2bf(v7); ah[7] = t; al[7] = f2bf(v7 - bf2f(t));
            } else {
                float v = valid ? pf0 : 0.f;       // k = 8
                short t = f2bf(v);
                ah[0] = t; al[0] = f2bf(v - bf2f(t));
                ah[1] = valid ? f2bf(1.0f) : (short)0;   // ones column, k = 9
            }

            // ---- prefetch next window (ranges tile contiguously) ----
            base += cnt;
            if (base < end_abs) PF(base);

            // ---- 6 MFMA: C = Al*Bh + Ah*Bl + Ah*Bh per N-tile ----
            f32x16 c0 = (f32x16)0.0f, c1 = (f32x16)0.0f;
            c0 = __builtin_amdgcn_mfma_f32_32x32x16_bf16(al, bh[0], c0, 0, 0, 0);
            c0 = __builtin_amdgcn_mfma_f32_32x32x16_bf16(ah, bl[0], c0, 0, 0, 0);
            c0 = __builtin_amdgcn_mfma_f32_32x32x16_bf16(ah, bh[0], c0, 0, 0, 0);
            c1 = __builtin_amdgcn_mfma_f32_32x32x16_bf16(al, bh[1], c1, 0, 0, 0);
            c1 = __builtin_amdgcn_mfma_f32_32x32x16_bf16(ah, bl[1], c1, 0, 0, 0);
            c1 = __builtin_amdgcn_mfma_f32_32x32x16_bf16(ah, bh[1], c1, 0, 0, 0);

            // ---- relu + row-sum (invalid rows are exactly 0) ----
            float s0 = 0.0f, s1 = 0.0f;
#pragma unroll
            for (int t = 0; t < 16; ++t) {
                s0 += fmaxf(c0[t], 0.0f);
                s1 += fmaxf(c1[t], 0.0f);
            }
            acc0 += s0;
            acc1 += s1;
        }

        // merge complementary row-halves (lanes L and L^32 hold same cols)
        acc0 += __shfl_xor(acc0, 32, 64);
        acc1 += __shfl_xor(acc1, 32, 64);
        // lane L stores channel L: L<32 -> col L (tile0), L>=32 -> col L (tile1)
        pooled[(size_t)(S0 + c) * 128 + side * 64 + lane] = h ? acc1 : acc0;
    }
}

// ---------------------------------------------------------------------------
// Kernel 3: head MLP. combined[B,128] @ Wc1[128,32] + bc1 -> relu
//           -> @ Wc2[32,1] + bc2 -> sigmoid.  (f32x4 row loads)
// ---------------------------------------------------------------------------
__global__ __launch_bounds__(256) void head_kernel(
    const float* __restrict__ pooled, const float* __restrict__ Wc1,
    const float* __restrict__ bc1, const float* __restrict__ Wc2,
    const float* __restrict__ bc2, float* __restrict__ out)
{
    __shared__ float sW[128 * 32];
    __shared__ float sb[32];
    __shared__ float sw2[32];

    for (int t = threadIdx.x; t < 128 * 32; t += 256) sW[t] = Wc1[t];
    if (threadIdx.x < 32) {
        sb[threadIdx.x] = bc1[threadIdx.x];
        sw2[threadIdx.x] = Wc2[threadIdx.x];
    }
    __syncthreads();

    const int lane = threadIdx.x & 63;
    const int wave = threadIdx.x >> 6;
    const int half = lane >> 5;
    const int j = lane & 31;

    const int row = blockIdx.x * 8 + wave * 2 + half;
    const f32x4* __restrict__ p4 =
        reinterpret_cast<const f32x4*>(pooled + (size_t)row * 128);

    float acc = sb[j];
#pragma unroll 8
    for (int k4 = 0; k4 < 32; ++k4) {
        f32x4 v = p4[k4];
        acc = fmaf(v.x, sW[(k4 * 4 + 0) * 32 + j], acc);
        acc = fmaf(v.y, sW[(k4 * 4 + 1) * 32 + j], acc);
        acc = fmaf(v.z, sW[(k4 * 4 + 2) * 32 + j], acc);
        acc = fmaf(v.w, sW[(k4 * 4 + 3) * 32 + j], acc);
    }

    float hh = fmaxf(acc, 0.0f) * sw2[j];
#pragma unroll
    for (int off = 16; off > 0; off >>= 1) hh += __shfl_xor(hh, off, 64);

    if (j == 0) {
        float logit = hh + bc2[0];
        out[row] = 1.0f / (1.0f + expf(-logit));
    }
}

// ---------------------------------------------------------------------------
extern "C" void kernel_launch(void* const* d_in, const int* in_sizes, int n_in,
                              void* d_out, int out_size, void* d_ws, size_t ws_size,
                              hipStream_t stream)
{
    const float* lfeats = (const float*)d_in[0];
    const float* rfeats = (const float*)d_in[1];
    const int*   lseg   = (const int*)d_in[2];
    const int*   rseg   = (const int*)d_in[3];
    const float* W1     = (const float*)d_in[4];
    const float* b1     = (const float*)d_in[5];
    const float* Wc1    = (const float*)d_in[6];
    const float* bc1    = (const float*)d_in[7];
    const float* Wc2    = (const float*)d_in[8];
    const float* bc2    = (const float*)d_in[9];
    float* out = (float*)d_out;

    const int n = in_sizes[2];  // N_UNITS per side

    float* pooled = (float*)d_ws;
    int* lstart = (int*)((char*)d_ws + (size_t)BATCH_C * 128 * sizeof(float));
    int* rstart = lstart + (BATCH_C + 16);

    seg_starts_kernel<<<dim3((n + 255) / 256, 2), 256, 0, stream>>>(
        lseg, rseg, n, lstart, rstart);

    pool_kernel<<<dim3(BATCH_C / (SPW * 4), 2), 256, 0, stream>>>(
        lfeats, rfeats, lstart, rstart, W1, b1, pooled, n);

    head_kernel<<<BATCH_C / 8, 256, 0, stream>>>(pooled, Wc1, bc1, Wc2, bc2, out);
}

// Round 7
// 48.672 us; speedup vs baseline: 1.0018x; 1.0018x over previous
//
#include <hip/hip_runtime.h>
#include <math.h>

#define BATCH_C 16384
#define SPW 4   // segments per wave

typedef float f32x4  __attribute__((ext_vector_type(4)));
typedef f32x4 __attribute__((aligned(4))) f32x4_u;   // dword-aligned vector load
typedef float f32x16 __attribute__((ext_vector_type(16)));
typedef short s16x8  __attribute__((ext_vector_type(8)));

// branchless RNE fp32->bf16 (no NaN inputs here), result in LOW 16 bits
static __device__ inline unsigned rlo_f(float x) {
    unsigned u = __float_as_uint(x);
    return (u + 0x7fffu + ((u >> 16) & 1u)) >> 16;
}
// same, result pre-positioned in HIGH 16 bits
static __device__ inline unsigned rhi_f(float x) {
    unsigned u = __float_as_uint(x);
    return (u + 0x7fffu + ((u >> 16) & 1u)) & 0xffff0000u;
}

// ---------------------------------------------------------------------------
// Kernel 1: segment boundary detection for BOTH sides (grid.y = side).
// start[b] = first index i with seg[i] >= b; start[BATCH]=n.
// ---------------------------------------------------------------------------
__global__ __launch_bounds__(256) void seg_starts_kernel(
    const int* __restrict__ lseg, const int* __restrict__ rseg, int n,
    int* __restrict__ lstart, int* __restrict__ rstart)
{
    const int* __restrict__ seg = blockIdx.y ? rseg : lseg;
    int* __restrict__ start = blockIdx.y ? rstart : lstart;
    int i = blockIdx.x * blockDim.x + threadIdx.x;
    if (i >= n) return;
    int s = seg[i];
    int prev = (i == 0) ? -1 : seg[i - 1];
    for (int b = prev + 1; b <= s; ++b) start[b] = i;
    if (i == n - 1) {
        for (int b = s + 1; b <= BATCH_C; ++b) start[b] = n;
    }
}

// ---------------------------------------------------------------------------
// Kernel 2: fused per-unit MLP (9->64, ReLU) + ragged segment sum via MFMA.
// fp32 accuracy via bf16 split: hi = trunc(v) (1 AND), lo = rne(v - hi);
// A*B ~= Ah*Bh + Ah*Bl + Al*Bh (dropped Al*Bl <= 2^-17 rel).
// B fragments (weights cols + bias row at k=9, hi/lo) built ONCE per block
// in LDS; waves read them with 4x ds_read_b128.
// A-build is branchless/uniform: convert 8 floats with integer ops, pack to
// 4 u32 pairs, fix up h-half (k8 + ones-column) and row validity with ~10
// cndmasks on the packed words. Invalid rows are all-zero -> C rows 0 ->
// relu(0)=0 -> unmasked row-sum epilogue.
// Windows (32 units) tile each segment; 2-deep register prefetch (ping-pong
// sets A/B, wave-uniform parity branch) keeps ~2 windows of global loads in
// flight. Flush per segment: shfl_xor(32) + 1 store (exactly-once).
// ---------------------------------------------------------------------------
__global__ __launch_bounds__(256, 4) void pool_kernel(
    const float* __restrict__ lfeats, const float* __restrict__ rfeats,
    const int* __restrict__ lstart, const int* __restrict__ rstart,
    const float* __restrict__ W1, const float* __restrict__ b1,
    float* __restrict__ pooled, int nunits)
{
    const int lane = threadIdx.x & 63;
    const int wv   = threadIdx.x >> 6;
    const int side = blockIdx.y;
    const int S0   = (blockIdx.x * 4 + wv) * SPW;
    const int r    = lane & 31;   // A row / B col within tile
    const int hh   = lane >> 5;   // k-half: 0 -> k0..7, 1 -> k8..15

    const float* __restrict__ feats = side ? rfeats : lfeats;
    const int*   __restrict__ start = side ? rstart : lstart;

    // ---- B fragments built once per block into LDS ----
    __shared__ short sBh[2][32][16];
    __shared__ short sBl[2][32][16];
    {
        const int t    = threadIdx.x;
        const int tile = t >> 7;
        const int col  = (t >> 2) & 31;
        const int k0   = (t & 3) * 4;
        const int ch   = tile * 32 + col;
#pragma unroll
        for (int q = 0; q < 4; ++q) {
            const int k = k0 + q;
            float v = 0.0f;
            if (k < 9) v = W1[k * 64 + ch];
            else if (k == 9) v = b1[ch];
            unsigned hi = rlo_f(v);                       // RNE hi for B (cheap, once)
            float d = v - __uint_as_float(hi << 16);
            sBh[tile][col][k] = (short)hi;
            sBl[tile][col][k] = (short)rlo_f(d);
        }
    }
    __syncthreads();
    const s16x8 bh0 = *reinterpret_cast<const s16x8*>(&sBh[0][r][hh * 8]);
    const s16x8 bh1 = *reinterpret_cast<const s16x8*>(&sBh[1][r][hh * 8]);
    const s16x8 bl0 = *reinterpret_cast<const s16x8*>(&sBl[0][r][hh * 8]);
    const s16x8 bl1 = *reinterpret_cast<const s16x8*>(&sBl[1][r][hh * 8]);

    // ---- segment boundaries ----
    int sv = start[S0 + (lane <= SPW ? lane : SPW)];
    const int s_abs = __shfl(sv, 0, 64);
    const int e1v = __shfl(sv, 1, 64);
    const int e2v = __shfl(sv, 2, 64);
    const int e3v = __shfl(sv, 3, 64);
    const int e4v = __shfl(sv, 4, 64);
    const int end_abs = e4v;

    // next window start after p (windows tile the range, capped at segment ends;
    // equal/empty boundaries collapse via the >= chain)
    auto segadv = [&](int p) -> int {
        int se = (p >= e1v) ? ((p >= e2v) ? ((p >= e3v) ? e4v : e3v) : e2v) : e1v;
        int w = se - p; if (w > 32) w = 32;
        return (p >= end_abs) ? p : (p + w);
    };

#define FETCH(POS, P0,P1,P2,P3,P4,P5,P6,P7) do {                          \
        int u_ = (POS) + r; if (u_ > nunits - 1) u_ = nunits - 1;         \
        const float* fp_ = feats + (size_t)u_ * 9;                        \
        if (hh == 0) {                                                    \
            f32x4 x0_ = *reinterpret_cast<const f32x4_u*>(fp_);           \
            f32x4 x1_ = *reinterpret_cast<const f32x4_u*>(fp_ + 4);       \
            P0 = x0_.x; P1 = x0_.y; P2 = x0_.z; P3 = x0_.w;               \
            P4 = x1_.x; P5 = x1_.y; P6 = x1_.z; P7 = x1_.w;               \
        } else {                                                          \
            P0 = fp_[8];                                                  \
        }                                                                 \
    } while (0)

#define WINBODY(CNT, P0,P1,P2,P3,P4,P5,P6,P7) do {                        \
    unsigned u0_ = __float_as_uint(P0), u1_ = __float_as_uint(P1);        \
    unsigned u2_ = __float_as_uint(P2), u3_ = __float_as_uint(P3);        \
    unsigned u4_ = __float_as_uint(P4), u5_ = __float_as_uint(P5);        \
    unsigned u6_ = __float_as_uint(P6), u7_ = __float_as_uint(P7);        \
    float d0_ = P0 - __uint_as_float(u0_ & 0xffff0000u);                  \
    float d1_ = P1 - __uint_as_float(u1_ & 0xffff0000u);                  \
    float d2_ = P2 - __uint_as_float(u2_ & 0xffff0000u);                  \
    float d3_ = P3 - __uint_as_float(u3_ & 0xffff0000u);                  \
    float d4_ = P4 - __uint_as_float(u4_ & 0xffff0000u);                  \
    float d5_ = P5 - __uint_as_float(u5_ & 0xffff0000u);                  \
    float d6_ = P6 - __uint_as_float(u6_ & 0xffff0000u);                  \
    float d7_ = P7 - __uint_as_float(u7_ & 0xffff0000u);                  \
    unsigned H01_ = (u0_ >> 16) | (u1_ & 0xffff0000u);                    \
    unsigned H23_ = (u2_ >> 16) | (u3_ & 0xffff0000u);                    \
    unsigned H45_ = (u4_ >> 16) | (u5_ & 0xffff0000u);                    \
    unsigned H67_ = (u6_ >> 16) | (u7_ & 0xffff0000u);                    \
    unsigned L01_ = rlo_f(d0_) | rhi_f(d1_);                              \
    unsigned L23_ = rlo_f(d2_) | rhi_f(d3_);                              \
    unsigned L45_ = rlo_f(d4_) | rhi_f(d5_);                              \
    unsigned L67_ = rlo_f(d6_) | rhi_f(d7_);                              \
    const bool val_  = (r < (CNT));                                       \
    const bool keep_ = val_ && (hh == 0);                                 \
    unsigned HH01_ = hh ? ((u0_ >> 16) | 0x3F800000u) : H01_;             \
    unsigned LL01_ = hh ? rlo_f(d0_) : L01_;                              \
    HH01_ = val_ ? HH01_ : 0u;                                            \
    LL01_ = val_ ? LL01_ : 0u;                                            \
    unsigned HH23_ = keep_ ? H23_ : 0u, HH45_ = keep_ ? H45_ : 0u;        \
    unsigned HH67_ = keep_ ? H67_ : 0u;                                   \
    unsigned LL23_ = keep_ ? L23_ : 0u, LL45_ = keep_ ? L45_ : 0u;        \
    unsigned LL67_ = keep_ ? L67_ : 0u;                                   \
    union { unsigned u[4]; s16x8 v; } Ah_, Al_;                           \
    Ah_.u[0] = HH01_; Ah_.u[1] = HH23_; Ah_.u[2] = HH45_; Ah_.u[3] = HH67_;\
    Al_.u[0] = LL01_; Al_.u[1] = LL23_; Al_.u[2] = LL45_; Al_.u[3] = LL67_;\
    if (posN < end_abs) { FETCH(posN, P0,P1,P2,P3,P4,P5,P6,P7); }         \
    posN = segadv(posN);                                                  \
    f32x16 cc0 = (f32x16)0.0f, cc1 = (f32x16)0.0f;                        \
    cc0 = __builtin_amdgcn_mfma_f32_32x32x16_bf16(Al_.v, bh0, cc0, 0,0,0);\
    cc0 = __builtin_amdgcn_mfma_f32_32x32x16_bf16(Ah_.v, bl0, cc0, 0,0,0);\
    cc0 = __builtin_amdgcn_mfma_f32_32x32x16_bf16(Ah_.v, bh0, cc0, 0,0,0);\
    cc1 = __builtin_amdgcn_mfma_f32_32x32x16_bf16(Al_.v, bh1, cc1, 0,0,0);\
    cc1 = __builtin_amdgcn_mfma_f32_32x32x16_bf16(Ah_.v, bl1, cc1, 0,0,0);\
    cc1 = __builtin_amdgcn_mfma_f32_32x32x16_bf16(Ah_.v, bh1, cc1, 0,0,0);\
    float s0_ = 0.0f, s1_ = 0.0f;                                         \
    _Pragma("unroll")                                                     \
    for (int t_ = 0; t_ < 16; ++t_) {                                     \
        s0_ += fmaxf(cc0[t_], 0.0f);                                      \
        s1_ += fmaxf(cc1[t_], 0.0f);                                      \
    }                                                                     \
    acc0 += s0_; acc1 += s1_;                                             \
} while (0)

    // ---- 2-deep prefetch prologue ----
    float A0=0,A1=0,A2=0,A3=0,A4=0,A5=0,A6=0,A7=0;
    float B0=0,B1=0,B2=0,B3=0,B4=0,B5=0,B6=0,B7=0;
    const int pa = s_abs;
    if (pa < end_abs) FETCH(pa, A0,A1,A2,A3,A4,A5,A6,A7);
    const int pb = segadv(pa);
    if (pb < end_abs) FETCH(pb, B0,B1,B2,B3,B4,B5,B6,B7);
    int posN = segadv(pb);

    float acc0 = 0.0f, acc1 = 0.0f;
    int parity = 0;
    int base = s_abs;
    const int earr[4] = {e1v, e2v, e3v, e4v};

#pragma unroll
    for (int c = 0; c < SPW; ++c) {
        const int ec = earr[c];
        while (base < ec) {
            int cnt = ec - base; if (cnt > 32) cnt = 32;
            if (parity == 0) { WINBODY(cnt, A0,A1,A2,A3,A4,A5,A6,A7); }
            else             { WINBODY(cnt, B0,B1,B2,B3,B4,B5,B6,B7); }
            parity ^= 1;
            base += cnt;
        }
        // merge complementary row-halves; lane L stores channel L
        acc0 += __shfl_xor(acc0, 32, 64);
        acc1 += __shfl_xor(acc1, 32, 64);
        pooled[(size_t)(S0 + c) * 128 + side * 64 + lane] = hh ? acc1 : acc0;
        acc0 = 0.0f; acc1 = 0.0f;
    }
#undef WINBODY
#undef FETCH
}

// ---------------------------------------------------------------------------
// Kernel 3: head MLP. combined[B,128] @ Wc1[128,32] + bc1 -> relu
//           -> @ Wc2[32,1] + bc2 -> sigmoid.  (f32x4 row loads)
// ---------------------------------------------------------------------------
__global__ __launch_bounds__(256) void head_kernel(
    const float* __restrict__ pooled, const float* __restrict__ Wc1,
    const float* __restrict__ bc1, const float* __restrict__ Wc2,
    const float* __restrict__ bc2, float* __restrict__ out)
{
    __shared__ float sW[128 * 32];
    __shared__ float sb[32];
    __shared__ float sw2[32];

    for (int t = threadIdx.x; t < 128 * 32; t += 256) sW[t] = Wc1[t];
    if (threadIdx.x < 32) {
        sb[threadIdx.x] = bc1[threadIdx.x];
        sw2[threadIdx.x] = Wc2[threadIdx.x];
    }
    __syncthreads();

    const int lane = threadIdx.x & 63;
    const int wave = threadIdx.x >> 6;
    const int half = lane >> 5;
    const int j = lane & 31;

    const int row = blockIdx.x * 8 + wave * 2 + half;
    const f32x4* __restrict__ p4 =
        reinterpret_cast<const f32x4*>(pooled + (size_t)row * 128);

    float acc = sb[j];
#pragma unroll 8
    for (int k4 = 0; k4 < 32; ++k4) {
        f32x4 v = p4[k4];
        acc = fmaf(v.x, sW[(k4 * 4 + 0) * 32 + j], acc);
        acc = fmaf(v.y, sW[(k4 * 4 + 1) * 32 + j], acc);
        acc = fmaf(v.z, sW[(k4 * 4 + 2) * 32 + j], acc);
        acc = fmaf(v.w, sW[(k4 * 4 + 3) * 32 + j], acc);
    }

    float hs = fmaxf(acc, 0.0f) * sw2[j];
#pragma unroll
    for (int off = 16; off > 0; off >>= 1) hs += __shfl_xor(hs, off, 64);

    if (j == 0) {
        float logit = hs + bc2[0];
        out[row] = 1.0f / (1.0f + expf(-logit));
    }
}

// ---------------------------------------------------------------------------
extern "C" void kernel_launch(void* const* d_in, const int* in_sizes, int n_in,
                              void* d_out, int out_size, void* d_ws, size_t ws_size,
                              hipStream_t stream)
{
    const float* lfeats = (const float*)d_in[0];
    const float* rfeats = (const float*)d_in[1];
    const int*   lseg   = (const int*)d_in[2];
    const int*   rseg   = (const int*)d_in[3];
    const float* W1     = (const float*)d_in[4];
    const float* b1     = (const float*)d_in[5];
    const float* Wc1    = (const float*)d_in[6];
    const float* bc1    = (const float*)d_in[7];
    const float* Wc2    = (const float*)d_in[8];
    const float* bc2    = (const float*)d_in[9];
    float* out = (float*)d_out;

    const int n = in_sizes[2];  // N_UNITS per side

    float* pooled = (float*)d_ws;
    int* lstart = (int*)((char*)d_ws + (size_t)BATCH_C * 128 * sizeof(float));
    int* rstart = lstart + (BATCH_C + 16);

    seg_starts_kernel<<<dim3((n + 255) / 256, 2), 256, 0, stream>>>(
        lseg, rseg, n, lstart, rstart);

    pool_kernel<<<dim3(BATCH_C / (SPW * 4), 2), 256, 0, stream>>>(
        lfeats, rfeats, lstart, rstart, W1, b1, pooled, n);

    head_kernel<<<BATCH_C / 8, 256, 0, stream>>>(pooled, Wc1, bc1, Wc2, bc2, out);
}

// Round 8
// 40.252 us; speedup vs baseline: 1.2113x; 1.2092x over previous
//
#include <hip/hip_runtime.h>
#include <math.h>

#define BATCH_C 16384
#define SPW 2   // segments per wave (each wave does BOTH sides + head for its rows)

typedef float f32x4  __attribute__((ext_vector_type(4)));
typedef f32x4 __attribute__((aligned(4))) f32x4_u;   // dword-aligned vector load
typedef float f32x16 __attribute__((ext_vector_type(16)));
typedef short s16x8  __attribute__((ext_vector_type(8)));

// branchless RNE fp32->bf16 (no NaN inputs here), result in LOW 16 bits
static __device__ inline unsigned rlo_f(float x) {
    unsigned u = __float_as_uint(x);
    return (u + 0x7fffu + ((u >> 16) & 1u)) >> 16;
}
// same, result pre-positioned in HIGH 16 bits
static __device__ inline unsigned rhi_f(float x) {
    unsigned u = __float_as_uint(x);
    return (u + 0x7fffu + ((u >> 16) & 1u)) & 0xffff0000u;
}

// ---------------------------------------------------------------------------
// Kernel 1: segment boundary detection for BOTH sides (grid.y = side).
// start[b] = first index i with seg[i] >= b; start[BATCH]=n.
// ---------------------------------------------------------------------------
__global__ __launch_bounds__(256) void seg_starts_kernel(
    const int* __restrict__ lseg, const int* __restrict__ rseg, int n,
    int* __restrict__ lstart, int* __restrict__ rstart)
{
    const int* __restrict__ seg = blockIdx.y ? rseg : lseg;
    int* __restrict__ start = blockIdx.y ? rstart : lstart;
    int i = blockIdx.x * blockDim.x + threadIdx.x;
    if (i >= n) return;
    int s = seg[i];
    int prev = (i == 0) ? -1 : seg[i - 1];
    for (int b = prev + 1; b <= s; ++b) start[b] = i;
    if (i == n - 1) {
        for (int b = s + 1; b <= BATCH_C; ++b) start[b] = n;
    }
}

// ---------------------------------------------------------------------------
// Kernel 2 (FUSED): per-unit MLP (9->64, ReLU) + ragged segment sum via MFMA
// for BOTH sides, then the head MLP for the wave's own rows — no global
// intermediate, no extra dispatches.
//
// Pool section: identical machinery to R7 (bf16 3-term split MFMA,
// 32-unit windows tiling each segment, 2-deep register prefetch, invalid
// rows zeroed -> relu(0)=0 -> unmasked row-sum). Flush now goes to a
// per-wave LDS rowbuf (combined[row][128]) instead of global.
// Head section (same wave, no __syncthreads needed): lanes split into
// 2 half-waves = the wave's 2 rows; 32 x { ds_read_b128 rowbuf (broadcast),
// ds_read_b128 sWT (per-lane, pad-132 => conflict-light) + 8 FMA }, then
// relu * Wc2, shfl_xor reduce over 32 hidden units, sigmoid, 1 store.
// Every output written exactly once -> deterministic.
// ---------------------------------------------------------------------------
__global__ __launch_bounds__(256, 4) void fused_kernel(
    const float* __restrict__ lfeats, const float* __restrict__ rfeats,
    const int* __restrict__ lstart, const int* __restrict__ rstart,
    const float* __restrict__ W1, const float* __restrict__ b1,
    const float* __restrict__ Wc1, const float* __restrict__ bc1,
    const float* __restrict__ Wc2, const float* __restrict__ bc2,
    float* __restrict__ out, int nunits)
{
    const int lane = threadIdx.x & 63;
    const int wv   = threadIdx.x >> 6;
    const int S0   = (blockIdx.x * 4 + wv) * SPW;
    const int r    = lane & 31;   // A row / B col within tile
    const int hh   = lane >> 5;   // k-half: 0 -> k0..7, 1 -> k8..15

    // ---- LDS ----
    __shared__ __align__(16) short sBh[2][32][16];
    __shared__ __align__(16) short sBl[2][32][16];
    __shared__ __align__(16) float sWT[32 * 132];   // Wc1 transposed, pad 132
    __shared__ float sb2[32];
    __shared__ float sw2v[32];
    __shared__ __align__(16) float rowbuf[4][SPW][128];

    // ---- stage B fragments (W1 cols + bias row at k=9, hi/lo) ----
    {
        const int t    = threadIdx.x;
        const int tile = t >> 7;
        const int col  = (t >> 2) & 31;
        const int k0   = (t & 3) * 4;
        const int ch   = tile * 32 + col;
#pragma unroll
        for (int q = 0; q < 4; ++q) {
            const int k = k0 + q;
            float v = 0.0f;
            if (k < 9) v = W1[k * 64 + ch];
            else if (k == 9) v = b1[ch];
            unsigned hi = rlo_f(v);
            float d = v - __uint_as_float(hi << 16);
            sBh[tile][col][k] = (short)hi;
            sBl[tile][col][k] = (short)rlo_f(d);
        }
    }
    // ---- stage Wc1 transposed + head vectors ----
    for (int idx = threadIdx.x; idx < 128 * 32; idx += 256) {
        sWT[(idx & 31) * 132 + (idx >> 5)] = Wc1[idx];
    }
    if (threadIdx.x < 32) {
        sb2[threadIdx.x]  = bc1[threadIdx.x];
        sw2v[threadIdx.x] = Wc2[threadIdx.x];
    }
    __syncthreads();

    const s16x8 bh0 = *reinterpret_cast<const s16x8*>(&sBh[0][r][hh * 8]);
    const s16x8 bh1 = *reinterpret_cast<const s16x8*>(&sBh[1][r][hh * 8]);
    const s16x8 bl0 = *reinterpret_cast<const s16x8*>(&sBl[0][r][hh * 8]);
    const s16x8 bl1 = *reinterpret_cast<const s16x8*>(&sBl[1][r][hh * 8]);

    // ---- per-lane boundary values for both sides ----
    const int bidx = S0 + (lane <= SPW ? lane : SPW);
    const int svl = lstart[bidx];
    const int svr = rstart[bidx];

#define FETCH(POS, P0,P1,P2,P3,P4,P5,P6,P7) do {                          \
        int u_ = (POS) + r; if (u_ > nunits - 1) u_ = nunits - 1;         \
        const float* fp_ = feats + (size_t)u_ * 9;                        \
        if (hh == 0) {                                                    \
            f32x4 x0_ = *reinterpret_cast<const f32x4_u*>(fp_);           \
            f32x4 x1_ = *reinterpret_cast<const f32x4_u*>(fp_ + 4);       \
            P0 = x0_.x; P1 = x0_.y; P2 = x0_.z; P3 = x0_.w;               \
            P4 = x1_.x; P5 = x1_.y; P6 = x1_.z; P7 = x1_.w;               \
        } else {                                                          \
            P0 = fp_[8];                                                  \
        }                                                                 \
    } while (0)

#define WINBODY(CNT, P0,P1,P2,P3,P4,P5,P6,P7) do {                        \
    unsigned u0_ = __float_as_uint(P0), u1_ = __float_as_uint(P1);        \
    unsigned u2_ = __float_as_uint(P2), u3_ = __float_as_uint(P3);        \
    unsigned u4_ = __float_as_uint(P4), u5_ = __float_as_uint(P5);        \
    unsigned u6_ = __float_as_uint(P6), u7_ = __float_as_uint(P7);        \
    float d0_ = P0 - __uint_as_float(u0_ & 0xffff0000u);                  \
    float d1_ = P1 - __uint_as_float(u1_ & 0xffff0000u);                  \
    float d2_ = P2 - __uint_as_float(u2_ & 0xffff0000u);                  \
    float d3_ = P3 - __uint_as_float(u3_ & 0xffff0000u);                  \
    float d4_ = P4 - __uint_as_float(u4_ & 0xffff0000u);                  \
    float d5_ = P5 - __uint_as_float(u5_ & 0xffff0000u);                  \
    float d6_ = P6 - __uint_as_float(u6_ & 0xffff0000u);                  \
    float d7_ = P7 - __uint_as_float(u7_ & 0xffff0000u);                  \
    unsigned H01_ = (u0_ >> 16) | (u1_ & 0xffff0000u);                    \
    unsigned H23_ = (u2_ >> 16) | (u3_ & 0xffff0000u);                    \
    unsigned H45_ = (u4_ >> 16) | (u5_ & 0xffff0000u);                    \
    unsigned H67_ = (u6_ >> 16) | (u7_ & 0xffff0000u);                    \
    unsigned L01_ = rlo_f(d0_) | rhi_f(d1_);                              \
    unsigned L23_ = rlo_f(d2_) | rhi_f(d3_);                              \
    unsigned L45_ = rlo_f(d4_) | rhi_f(d5_);                              \
    unsigned L67_ = rlo_f(d6_) | rhi_f(d7_);                              \
    const bool val_  = (r < (CNT));                                       \
    const bool keep_ = val_ && (hh == 0);                                 \
    unsigned HH01_ = hh ? ((u0_ >> 16) | 0x3F800000u) : H01_;             \
    unsigned LL01_ = hh ? rlo_f(d0_) : L01_;                              \
    HH01_ = val_ ? HH01_ : 0u;                                            \
    LL01_ = val_ ? LL01_ : 0u;                                            \
    unsigned HH23_ = keep_ ? H23_ : 0u, HH45_ = keep_ ? H45_ : 0u;        \
    unsigned HH67_ = keep_ ? H67_ : 0u;                                   \
    unsigned LL23_ = keep_ ? L23_ : 0u, LL45_ = keep_ ? L45_ : 0u;        \
    unsigned LL67_ = keep_ ? L67_ : 0u;                                   \
    union { unsigned u[4]; s16x8 v; } Ah_, Al_;                           \
    Ah_.u[0] = HH01_; Ah_.u[1] = HH23_; Ah_.u[2] = HH45_; Ah_.u[3] = HH67_;\
    Al_.u[0] = LL01_; Al_.u[1] = LL23_; Al_.u[2] = LL45_; Al_.u[3] = LL67_;\
    if (posN < end_abs) { FETCH(posN, P0,P1,P2,P3,P4,P5,P6,P7); }         \
    posN = segadv(posN);                                                  \
    f32x16 cc0 = (f32x16)0.0f, cc1 = (f32x16)0.0f;                        \
    cc0 = __builtin_amdgcn_mfma_f32_32x32x16_bf16(Al_.v, bh0, cc0, 0,0,0);\
    cc0 = __builtin_amdgcn_mfma_f32_32x32x16_bf16(Ah_.v, bl0, cc0, 0,0,0);\
    cc0 = __builtin_amdgcn_mfma_f32_32x32x16_bf16(Ah_.v, bh0, cc0, 0,0,0);\
    cc1 = __builtin_amdgcn_mfma_f32_32x32x16_bf16(Al_.v, bh1, cc1, 0,0,0);\
    cc1 = __builtin_amdgcn_mfma_f32_32x32x16_bf16(Ah_.v, bl1, cc1, 0,0,0);\
    cc1 = __builtin_amdgcn_mfma_f32_32x32x16_bf16(Ah_.v, bh1, cc1, 0,0,0);\
    float s0_ = 0.0f, s1_ = 0.0f;                                         \
    _Pragma("unroll")                                                     \
    for (int t_ = 0; t_ < 16; ++t_) {                                     \
        s0_ += fmaxf(cc0[t_], 0.0f);                                      \
        s1_ += fmaxf(cc1[t_], 0.0f);                                      \
    }                                                                     \
    acc0 += s0_; acc1 += s1_;                                             \
} while (0)

    // ================= POOL: both sides into rowbuf =================
    for (int side = 0; side < 2; ++side) {
        const float* __restrict__ feats = side ? rfeats : lfeats;
        const int sv = side ? svr : svl;
        const int s_abs = __shfl(sv, 0, 64);
        const int e1v = __shfl(sv, 1, 64);
        const int e2v = __shfl(sv, 2, 64);
        const int end_abs = e2v;

        auto segadv = [&](int p) -> int {
            int se = (p >= e1v) ? e2v : e1v;
            int w = se - p; if (w > 32) w = 32;
            return (p >= end_abs) ? p : (p + w);
        };

        float A0=0,A1=0,A2=0,A3=0,A4=0,A5=0,A6=0,A7=0;
        float B0=0,B1=0,B2=0,B3=0,B4=0,B5=0,B6=0,B7=0;
        const int pa = s_abs;
        if (pa < end_abs) FETCH(pa, A0,A1,A2,A3,A4,A5,A6,A7);
        const int pb = segadv(pa);
        if (pb < end_abs) FETCH(pb, B0,B1,B2,B3,B4,B5,B6,B7);
        int posN = segadv(pb);

        float acc0 = 0.0f, acc1 = 0.0f;
        int parity = 0;
        int base = s_abs;
        const int earr[SPW] = {e1v, e2v};

#pragma unroll
        for (int c = 0; c < SPW; ++c) {
            const int ec = earr[c];
            while (base < ec) {
                int cnt = ec - base; if (cnt > 32) cnt = 32;
                if (parity == 0) { WINBODY(cnt, A0,A1,A2,A3,A4,A5,A6,A7); }
                else             { WINBODY(cnt, B0,B1,B2,B3,B4,B5,B6,B7); }
                parity ^= 1;
                base += cnt;
            }
            // merge complementary row-halves; lane L holds channel L
            acc0 += __shfl_xor(acc0, 32, 64);
            acc1 += __shfl_xor(acc1, 32, 64);
            rowbuf[wv][c][side * 64 + lane] = hh ? acc1 : acc0;
            acc0 = 0.0f; acc1 = 0.0f;
        }
    }
#undef WINBODY
#undef FETCH

    // drain rowbuf ds_writes (same-wave RAW; no cross-wave sharing)
    asm volatile("s_waitcnt lgkmcnt(0)" ::: "memory");

    // ================= HEAD: 2 rows per wave (half-wave each) =================
    {
        const int j = lane & 31;          // hidden unit
        const float* __restrict__ rb = &rowbuf[wv][hh][0];   // row = S0 + hh
        const float* __restrict__ wt = &sWT[j * 132];

        float accA = sb2[j], accB = 0.0f;
#pragma unroll 8
        for (int q = 0; q < 32; ++q) {
            f32x4 v = *reinterpret_cast<const f32x4*>(rb + q * 4);
            f32x4 w = *reinterpret_cast<const f32x4*>(wt + q * 4);
            accA = fmaf(v.x, w.x, accA);
            accB = fmaf(v.y, w.y, accB);
            accA = fmaf(v.z, w.z, accA);
            accB = fmaf(v.w, w.w, accB);
        }
        float hsv = fmaxf(accA + accB, 0.0f) * sw2v[j];
#pragma unroll
        for (int off = 16; off > 0; off >>= 1) hsv += __shfl_xor(hsv, off, 64);

        if (j == 0) {
            float logit = hsv + bc2[0];
            out[S0 + hh] = 1.0f / (1.0f + expf(-logit));
        }
    }
}

// ---------------------------------------------------------------------------
extern "C" void kernel_launch(void* const* d_in, const int* in_sizes, int n_in,
                              void* d_out, int out_size, void* d_ws, size_t ws_size,
                              hipStream_t stream)
{
    const float* lfeats = (const float*)d_in[0];
    const float* rfeats = (const float*)d_in[1];
    const int*   lseg   = (const int*)d_in[2];
    const int*   rseg   = (const int*)d_in[3];
    const float* W1     = (const float*)d_in[4];
    const float* b1     = (const float*)d_in[5];
    const float* Wc1    = (const float*)d_in[6];
    const float* bc1    = (const float*)d_in[7];
    const float* Wc2    = (const float*)d_in[8];
    const float* bc2    = (const float*)d_in[9];
    float* out = (float*)d_out;

    const int n = in_sizes[2];  // N_UNITS per side

    int* lstart = (int*)d_ws;
    int* rstart = lstart + (BATCH_C + 16);

    seg_starts_kernel<<<dim3((n + 255) / 256, 2), 256, 0, stream>>>(
        lseg, rseg, n, lstart, rstart);

    fused_kernel<<<BATCH_C / (SPW * 4), 256, 0, stream>>>(
        lfeats, rfeats, lstart, rstart, W1, b1, Wc1, bc1, Wc2, bc2, out, n);
}

// Round 9
// 36.448 us; speedup vs baseline: 1.3377x; 1.1044x over previous
//
#include <hip/hip_runtime.h>
#include <math.h>

#define BATCH_C 16384
#define SPW 2   // segments (batch rows) per wave; each wave does both sides + head

typedef float f32x4  __attribute__((ext_vector_type(4)));
typedef f32x4 __attribute__((aligned(4))) f32x4_u;   // dword-aligned vector load
typedef float f32x16 __attribute__((ext_vector_type(16)));
typedef short s16x8  __attribute__((ext_vector_type(8)));

typedef union { unsigned u[4]; s16x8 v; } abfrag_t;

// branchless RNE fp32->bf16 (no NaN inputs here), result in LOW 16 bits
static __device__ inline unsigned rlo_f(float x) {
    unsigned u = __float_as_uint(x);
    return (u + 0x7fffu + ((u >> 16) & 1u)) >> 16;
}
// same, result pre-positioned in HIGH 16 bits
static __device__ inline unsigned rhi_f(float x) {
    unsigned u = __float_as_uint(x);
    return (u + 0x7fffu + ((u >> 16) & 1u)) & 0xffff0000u;
}

// ---------------------------------------------------------------------------
// Kernel 1: segment boundary detection for BOTH sides (grid.y = side).
// start[b] = first index i with seg[i] >= b; start[BATCH]=n.
// ---------------------------------------------------------------------------
__global__ __launch_bounds__(256) void seg_starts_kernel(
    const int* __restrict__ lseg, const int* __restrict__ rseg, int n,
    int* __restrict__ lstart, int* __restrict__ rstart)
{
    const int* __restrict__ seg = blockIdx.y ? rseg : lseg;
    int* __restrict__ start = blockIdx.y ? rstart : lstart;
    int i = blockIdx.x * blockDim.x + threadIdx.x;
    if (i >= n) return;
    int s = seg[i];
    int prev = (i == 0) ? -1 : seg[i - 1];
    for (int b = prev + 1; b <= s; ++b) start[b] = i;
    if (i == n - 1) {
        for (int b = s + 1; b <= BATCH_C; ++b) start[b] = n;
    }
}

// ---------------------------------------------------------------------------
// Kernel 2 (FUSED): per-unit MLP (9->64, ReLU) + ragged segment sum via MFMA
// for BOTH sides processed as two CONCURRENT streams in one loop body
// (single basic block -> scheduler interleaves the 4 independent MFMA
// chains and the two conversion blocks), then the head MLP for the wave's
// own 2 rows. bf16 3-term split keeps fp32-level accuracy (absmax ~1e-4).
// launch_bounds(256,2): accumulators stay in VGPRs (no AGPR move tax).
// Persistent kZ zero vector seeds each MFMA chain (D != C) - no per-window
// accumulator zero-init. Branchless FETCH + branchless dummy prefetch
// (clamped to unit 0, L2-resident) keep the body branch-free except the
// rare per-segment flush.
// ---------------------------------------------------------------------------
__global__ __launch_bounds__(256, 2) void fused_kernel(
    const float* __restrict__ lfeats, const float* __restrict__ rfeats,
    const int* __restrict__ lstart, const int* __restrict__ rstart,
    const float* __restrict__ W1, const float* __restrict__ b1,
    const float* __restrict__ Wc1, const float* __restrict__ bc1,
    const float* __restrict__ Wc2, const float* __restrict__ bc2,
    float* __restrict__ out, int nunits)
{
    const int lane = threadIdx.x & 63;
    const int wv   = threadIdx.x >> 6;
    const int S0   = (blockIdx.x * 4 + wv) * SPW;
    const int r    = lane & 31;   // A row / B col within tile
    const int hh   = lane >> 5;   // k-half: 0 -> k0..7, 1 -> k8..15
    const int nmax = nunits - 1;
    const int ofs1 = hh ? 5 : 4;  // x1 window: f4..7 (hh=0) / f5..8 (hh=1)

    // ---- LDS ----
    __shared__ __align__(16) short sBh[2][32][16];
    __shared__ __align__(16) short sBl[2][32][16];
    __shared__ __align__(16) float sWT[32 * 132];   // Wc1 transposed, pad 132
    __shared__ float sb2[32];
    __shared__ float sw2v[32];
    __shared__ __align__(16) float rowbuf[4][SPW][128];

    // ---- stage B fragments (W1 cols + bias row at k=9, hi/lo) ----
    {
        const int t    = threadIdx.x;
        const int tile = t >> 7;
        const int col  = (t >> 2) & 31;
        const int k0   = (t & 3) * 4;
        const int ch   = tile * 32 + col;
#pragma unroll
        for (int q = 0; q < 4; ++q) {
            const int k = k0 + q;
            float v = 0.0f;
            if (k < 9) v = W1[k * 64 + ch];
            else if (k == 9) v = b1[ch];
            unsigned hi = rlo_f(v);
            float d = v - __uint_as_float(hi << 16);
            sBh[tile][col][k] = (short)hi;
            sBl[tile][col][k] = (short)rlo_f(d);
        }
    }
    for (int idx = threadIdx.x; idx < 128 * 32; idx += 256) {
        sWT[(idx & 31) * 132 + (idx >> 5)] = Wc1[idx];
    }
    if (threadIdx.x < 32) {
        sb2[threadIdx.x]  = bc1[threadIdx.x];
        sw2v[threadIdx.x] = Wc2[threadIdx.x];
    }
    __syncthreads();

    const s16x8 bh0 = *reinterpret_cast<const s16x8*>(&sBh[0][r][hh * 8]);
    const s16x8 bh1 = *reinterpret_cast<const s16x8*>(&sBh[1][r][hh * 8]);
    const s16x8 bl0 = *reinterpret_cast<const s16x8*>(&sBl[0][r][hh * 8]);
    const s16x8 bl1 = *reinterpret_cast<const s16x8*>(&sBl[1][r][hh * 8]);

    // persistent zero accumulator seed (MFMA D != C)
    const f32x16 kZ = (f32x16)0.0f;

    // ---- pre-zero this wave's rowbuf (covers empty segments) ----
    rowbuf[wv][0][lane] = 0.0f;  rowbuf[wv][0][64 + lane] = 0.0f;
    rowbuf[wv][1][lane] = 0.0f;  rowbuf[wv][1][64 + lane] = 0.0f;

    // ---- segment boundaries for both sides ----
    const int bidx = S0 + (lane <= SPW ? lane : SPW);
    const int svl = lstart[bidx];
    const int svr = rstart[bidx];
    const int sLv = __shfl(svl, 0, 64);
    const int e1L = __shfl(svl, 1, 64);
    const int e2L = __shfl(svl, 2, 64);
    const int sRv = __shfl(svr, 0, 64);
    const int e1R = __shfl(svr, 1, 64);
    const int e2R = __shfl(svr, 2, 64);
    const int endL = e2L, endR = e2R;

#define FETCH_(F, POS, Q0,Q1,Q2,Q3,Q4,Q5,Q6,Q7) do {                      \
        int u_ = (POS) + r; if (u_ > nmax) u_ = nmax;                     \
        const float* fp_ = (F) + (size_t)u_ * 9;                          \
        f32x4 x0_ = *reinterpret_cast<const f32x4_u*>(fp_);               \
        f32x4 x1_ = *reinterpret_cast<const f32x4_u*>(fp_ + ofs1);        \
        Q0 = hh ? x1_.w : x0_.x;                                          \
        Q1 = x0_.y; Q2 = x0_.z; Q3 = x0_.w;                               \
        Q4 = x1_.x; Q5 = x1_.y; Q6 = x1_.z; Q7 = x1_.w;                   \
    } while (0)

#define CONV_(Q0,Q1,Q2,Q3,Q4,Q5,Q6,Q7, CNT, AH, AL) do {                  \
    unsigned u0_=__float_as_uint(Q0), u1_=__float_as_uint(Q1),            \
             u2_=__float_as_uint(Q2), u3_=__float_as_uint(Q3),            \
             u4_=__float_as_uint(Q4), u5_=__float_as_uint(Q5),            \
             u6_=__float_as_uint(Q6), u7_=__float_as_uint(Q7);            \
    float d0_=Q0-__uint_as_float(u0_&0xffff0000u);                        \
    float d1_=Q1-__uint_as_float(u1_&0xffff0000u);                        \
    float d2_=Q2-__uint_as_float(u2_&0xffff0000u);                        \
    float d3_=Q3-__uint_as_float(u3_&0xffff0000u);                        \
    float d4_=Q4-__uint_as_float(u4_&0xffff0000u);                        \
    float d5_=Q5-__uint_as_float(u5_&0xffff0000u);                        \
    float d6_=Q6-__uint_as_float(u6_&0xffff0000u);                        \
    float d7_=Q7-__uint_as_float(u7_&0xffff0000u);                        \
    unsigned h01_=(u0_>>16)|(hh?0x3F800000u:(u1_&0xffff0000u));           \
    unsigned l01_=rlo_f(d0_)|(hh?0u:rhi_f(d1_));                          \
    unsigned h23_=(u2_>>16)|(u3_&0xffff0000u);                            \
    unsigned h45_=(u4_>>16)|(u5_&0xffff0000u);                            \
    unsigned h67_=(u6_>>16)|(u7_&0xffff0000u);                            \
    unsigned l23_=rlo_f(d2_)|rhi_f(d3_);                                  \
    unsigned l45_=rlo_f(d4_)|rhi_f(d5_);                                  \
    unsigned l67_=rlo_f(d6_)|rhi_f(d7_);                                  \
    const bool v_ = (r < (CNT));                                          \
    const bool k_ = v_ && (hh == 0);                                      \
    AH.u[0]=v_?h01_:0u; AL.u[0]=v_?l01_:0u;                               \
    AH.u[1]=k_?h23_:0u; AL.u[1]=k_?l23_:0u;                               \
    AH.u[2]=k_?h45_:0u; AL.u[2]=k_?l45_:0u;                               \
    AH.u[3]=k_?h67_:0u; AL.u[3]=k_?l67_:0u;                               \
} while (0)

#define MFMAEPI_(AH, AL, A0, A1) do {                                     \
    f32x16 c0_ = __builtin_amdgcn_mfma_f32_32x32x16_bf16(AL.v, bh0, kZ, 0,0,0); \
    c0_ = __builtin_amdgcn_mfma_f32_32x32x16_bf16(AH.v, bl0, c0_, 0,0,0); \
    c0_ = __builtin_amdgcn_mfma_f32_32x32x16_bf16(AH.v, bh0, c0_, 0,0,0); \
    f32x16 c1_ = __builtin_amdgcn_mfma_f32_32x32x16_bf16(AL.v, bh1, kZ, 0,0,0); \
    c1_ = __builtin_amdgcn_mfma_f32_32x32x16_bf16(AH.v, bl1, c1_, 0,0,0); \
    c1_ = __builtin_amdgcn_mfma_f32_32x32x16_bf16(AH.v, bh1, c1_, 0,0,0); \
    float sA_=0.f,sB_=0.f,sC_=0.f,sD_=0.f,tA_=0.f,tB_=0.f,tC_=0.f,tD_=0.f;\
    _Pragma("unroll")                                                     \
    for (int t_=0; t_<4; ++t_) {                                          \
        sA_+=fmaxf(c0_[t_],0.f);    sB_+=fmaxf(c0_[t_+4],0.f);            \
        sC_+=fmaxf(c0_[t_+8],0.f);  sD_+=fmaxf(c0_[t_+12],0.f);           \
        tA_+=fmaxf(c1_[t_],0.f);    tB_+=fmaxf(c1_[t_+4],0.f);            \
        tC_+=fmaxf(c1_[t_+8],0.f);  tD_+=fmaxf(c1_[t_+12],0.f);           \
    }                                                                     \
    A0 += (sA_+sB_)+(sC_+sD_);                                            \
    A1 += (tA_+tB_)+(tC_+tD_);                                            \
} while (0)

#define STEP_(S) do {                                                     \
    int cnt_ = ec##S - base##S; if (cnt_ > 32) cnt_ = 32;                 \
    abfrag_t AH_, AL_;                                                    \
    CONV_(p0##S,p1##S,p2##S,p3##S,p4##S,p5##S,p6##S,p7##S, cnt_, AH_, AL_);\
    int nxt_ = base##S + cnt_;                                            \
    int fpos_ = (nxt_ < end##S) ? nxt_ : 0;  /* dummy fetch: L2-resident */\
    FETCH_(f##S, fpos_, p0##S,p1##S,p2##S,p3##S,p4##S,p5##S,p6##S,p7##S); \
    MFMAEPI_(AH_, AL_, ac0##S, ac1##S);                                   \
    base##S = nxt_;                                                       \
} while (0)

#define FLUSH_(S, SIDEOFS) do {                                           \
    if (base##S >= ec##S) {                                               \
        ac0##S += __shfl_xor(ac0##S, 32, 64);                             \
        ac1##S += __shfl_xor(ac1##S, 32, 64);                             \
        if (cs##S < SPW)                                                  \
            rowbuf[wv][cs##S][(SIDEOFS) + lane] = hh ? ac1##S : ac0##S;   \
        ac0##S = 0.0f; ac1##S = 0.0f;                                     \
        ++cs##S; ec##S = e2##S;                                           \
    }                                                                     \
} while (0)

    // ---- per-side stream state ----
    const float* __restrict__ fL = lfeats;
    const float* __restrict__ fR = rfeats;
    int baseL = sLv, baseR = sRv;
    int csL, ecL, csR, ecR;
    if (baseL >= e1L) { csL = 1; ecL = e2L; } else { csL = 0; ecL = e1L; }
    if (baseR >= e1R) { csR = 1; ecR = e2R; } else { csR = 0; ecR = e1R; }
    float ac0L = 0.f, ac1L = 0.f, ac0R = 0.f, ac1R = 0.f;
    float p0L=0,p1L=0,p2L=0,p3L=0,p4L=0,p5L=0,p6L=0,p7L=0;
    float p0R=0,p1R=0,p2R=0,p3R=0,p4R=0,p5R=0,p6R=0,p7R=0;

    if (baseL < endL) FETCH_(fL, baseL, p0L,p1L,p2L,p3L,p4L,p5L,p6L,p7L);
    if (baseR < endR) FETCH_(fR, baseR, p0R,p1R,p2R,p3R,p4R,p5R,p6R,p7R);

    bool aL = baseL < endL, aR = baseR < endR;
    while (aL && aR) {           // fused dual-stream body: one big BB
        STEP_(L);
        STEP_(R);
        FLUSH_(L, 0);
        FLUSH_(R, 64);
        aL = baseL < endL; aR = baseR < endR;
    }
    while (aL) { STEP_(L); FLUSH_(L, 0);  aL = baseL < endL; }
    while (aR) { STEP_(R); FLUSH_(R, 64); aR = baseR < endR; }

#undef FLUSH_
#undef STEP_
#undef MFMAEPI_
#undef CONV_
#undef FETCH_

    // drain rowbuf ds_writes (same-wave RAW; no cross-wave sharing)
    asm volatile("s_waitcnt lgkmcnt(0)" ::: "memory");

    // ================= HEAD: 2 rows per wave (half-wave each) =================
    {
        const int j = lane & 31;          // hidden unit
        const float* __restrict__ rb = &rowbuf[wv][hh][0];   // row = S0 + hh
        const float* __restrict__ wt = &sWT[j * 132];

        float accA = sb2[j], accB = 0.0f;
#pragma unroll 8
        for (int q = 0; q < 32; ++q) {
            f32x4 v = *reinterpret_cast<const f32x4*>(rb + q * 4);
            f32x4 w = *reinterpret_cast<const f32x4*>(wt + q * 4);
            accA = fmaf(v.x, w.x, accA);
            accB = fmaf(v.y, w.y, accB);
            accA = fmaf(v.z, w.z, accA);
            accB = fmaf(v.w, w.w, accB);
        }
        float hsv = fmaxf(accA + accB, 0.0f) * sw2v[j];
#pragma unroll
        for (int off = 16; off > 0; off >>= 1) hsv += __shfl_xor(hsv, off, 64);

        if (j == 0) {
            float logit = hsv + bc2[0];
            out[S0 + hh] = 1.0f / (1.0f + expf(-logit));
        }
    }
}

// ---------------------------------------------------------------------------
extern "C" void kernel_launch(void* const* d_in, const int* in_sizes, int n_in,
                              void* d_out, int out_size, void* d_ws, size_t ws_size,
                              hipStream_t stream)
{
    const float* lfeats = (const float*)d_in[0];
    const float* rfeats = (const float*)d_in[1];
    const int*   lseg   = (const int*)d_in[2];
    const int*   rseg   = (const int*)d_in[3];
    const float* W1     = (const float*)d_in[4];
    const float* b1     = (const float*)d_in[5];
    const float* Wc1    = (const float*)d_in[6];
    const float* bc1    = (const float*)d_in[7];
    const float* Wc2    = (const float*)d_in[8];
    const float* bc2    = (const float*)d_in[9];
    float* out = (float*)d_out;

    const int n = in_sizes[2];  // N_UNITS per side

    int* lstart = (int*)d_ws;
    int* rstart = lstart + (BATCH_C + 16);

    seg_starts_kernel<<<dim3((n + 255) / 256, 2), 256, 0, stream>>>(
        lseg, rseg, n, lstart, rstart);

    fused_kernel<<<BATCH_C / (SPW * 4), 256, 0, stream>>>(
        lfeats, rfeats, lstart, rstart, W1, b1, Wc1, bc1, Wc2, bc2, out, n);
}